// Round 1
// baseline (1078.378 us; speedup 1.0000x reference)
//
#include <hip/hip_runtime.h>
#include <math.h>

#define B 64
#define Lw 2048
#define Hd 1024
#define Vd 50257

// ws offsets (in floats)
#define WS_XH4    0          // packed [x;h] activations: 2048*64 = 131072
#define WS_GATES  131072     // gatesT [4096][64]        = 262144
#define WS_CAT4   393216     // packed [h1;context]      = 131072
#define WS_ENERGY 524288     // energies [64][2048]      = 131072
#define WS_PART   655360     // 16*64 partials * 1032    = 1056768
#define WS_MS     1712128    // per-b (m, s)             = 128
#define WS_CONCAT 1712256    // packed concat_out        = 65536

// d_out offsets (floats): output[B][V], h1[1][B][H], c1[1][B][H], attn[B][1][L]
#define OUT_H1   3216448
#define OUT_C1   3281984
#define OUT_ATTN 3347520

#define NCHUNK 16
#define LCHUNK 128
#define PSTRIDE 1032

__device__ __forceinline__ float sigm(float x) { return 1.f / (1.f + expf(-x)); }

// ---------------- embed + pack [x ; h_prev] transposed: xh4[(k/4)*256 + b*4 + k%4]
__global__ void k_embed(const int* __restrict__ seq, const float* __restrict__ emb,
                        const float* __restrict__ h0, float* __restrict__ xh)
{
    int b = blockIdx.x;
    int t = threadIdx.x;               // handles h = t*4 .. t*4+3
    int tok = seq[b];
    float4 xv = *(const float4*)(emb + (size_t)tok * Hd + t * 4);
    float4 hv = *(const float4*)(h0 + (size_t)b * Hd + t * 4);
    ((float4*)xh)[t * B + b] = xv;            // k = t*4 (x part)
    ((float4*)xh)[(256 + t) * B + b] = hv;    // k = 1024 + t*4 (h part)
}

// ---------------- generic skinny GEMM: out[b, row] = act[b, :] . W[row, :] (+bias)
// act is packed-transposed: float4 index k4*64 + lane.  lane = b.
// MODE 0: gatesT store [row][B], bias1+bias2
// MODE 1: tanh, packed4 store (feeds next GEMM), bias1
// MODE 2: plain [b][row] store (d_out), bias1
template<int K1, int K2, int ROWS, int MODE>
__global__ void k_gemm(const float4* __restrict__ act,
                       const float* __restrict__ W1, const float* __restrict__ W2,
                       const float* __restrict__ b1, const float* __restrict__ b2,
                       int N, float* __restrict__ out, int ldout)
{
    int wave = threadIdx.x >> 6;
    int lane = threadIdx.x & 63;
    int r0 = (blockIdx.x * 4 + wave) * ROWS;
    if (r0 >= N) return;
    int rm = N - r0;   // valid rows in this group (>= 1)

    const float* wp1[ROWS];
#pragma unroll
    for (int r = 0; r < ROWS; ++r) {
        int rr = r0 + (r < rm ? r : (rm - 1));   // clamp (dup loads are safe)
        wp1[r] = W1 + (size_t)rr * K1;
    }
    float acc[ROWS];
#pragma unroll
    for (int r = 0; r < ROWS; ++r) acc[r] = 0.f;

#pragma unroll 2
    for (int k4 = 0; k4 < K1 / 4; ++k4) {
        float4 a = act[k4 * B + lane];
#pragma unroll
        for (int r = 0; r < ROWS; ++r) {
            float4 w = *(const float4*)(wp1[r] + k4 * 4);
            acc[r] += a.x * w.x + a.y * w.y + a.z * w.z + a.w * w.w;
        }
    }
    if constexpr (K2 > 0) {
        const float* wp2[ROWS];
#pragma unroll
        for (int r = 0; r < ROWS; ++r) {
            int rr = r0 + (r < rm ? r : (rm - 1));
            wp2[r] = W2 + (size_t)rr * K2;
        }
#pragma unroll 2
        for (int k4 = 0; k4 < K2 / 4; ++k4) {
            float4 a = act[(K1 / 4 + k4) * B + lane];
#pragma unroll
            for (int r = 0; r < ROWS; ++r) {
                float4 w = *(const float4*)(wp2[r] + k4 * 4);
                acc[r] += a.x * w.x + a.y * w.y + a.z * w.z + a.w * w.w;
            }
        }
    }

#pragma unroll
    for (int r = 0; r < ROWS; ++r) {
        if (r < rm) {
            int row = r0 + r;
            if constexpr (MODE == 0) {
                out[(size_t)row * B + lane] = acc[r] + b1[row] + b2[row];
            } else if constexpr (MODE == 1) {
                out[(row >> 2) * 256 + lane * 4 + (row & 3)] = tanhf(acc[r] + b1[row]);
            } else {
                out[(size_t)lane * ldout + row] = acc[r] + b1[row];
            }
        }
    }
}

// ---------------- LSTM pointwise (PyTorch gate order i,f,g,o)
__global__ void k_pointwise(const float* __restrict__ gatesT, const float* __restrict__ c0,
                            float* __restrict__ h1o, float* __restrict__ c1o,
                            float* __restrict__ cat)
{
    int wave = threadIdx.x >> 6, lane = threadIdx.x & 63;
    int hh = blockIdx.x * 4 + wave;
    float gi = gatesT[(size_t)(0 * Hd + hh) * B + lane];
    float gf = gatesT[(size_t)(1 * Hd + hh) * B + lane];
    float gg = gatesT[(size_t)(2 * Hd + hh) * B + lane];
    float go = gatesT[(size_t)(3 * Hd + hh) * B + lane];
    float c  = c0[(size_t)lane * Hd + hh];
    float c1 = sigm(gf) * c + sigm(gi) * tanhf(gg);
    float h1 = sigm(go) * tanhf(c1);
    h1o[(size_t)lane * Hd + hh] = h1;
    c1o[(size_t)lane * Hd + hh] = c1;
    cat[(hh >> 2) * 256 + lane * 4 + (hh & 3)] = h1;   // packed, k = hh
}

// ---------------- fused energies + online-softmax context partials (one enc pass)
__global__ void k_attn_part(const float* __restrict__ enc, const float* __restrict__ h1,
                            float* __restrict__ energy, float* __restrict__ part)
{
    int chunk = blockIdx.x, b = blockIdx.y;
    int wave = threadIdx.x >> 6, lane = threadIdx.x & 63;

    float4 qv[4], ctx[4];
#pragma unroll
    for (int q = 0; q < 4; ++q) {
        qv[q] = *(const float4*)(h1 + (size_t)b * Hd + q * 256 + lane * 4);
        ctx[q] = make_float4(0.f, 0.f, 0.f, 0.f);
    }
    float m = -INFINITY, s = 0.f;

    for (int i = 0; i < LCHUNK / 4; ++i) {
        int l = chunk * LCHUNK + i * 4 + wave;
        const float* ep = enc + ((size_t)l * B + b) * Hd;
        float4 ev[4];
#pragma unroll
        for (int q = 0; q < 4; ++q) ev[q] = *(const float4*)(ep + q * 256 + lane * 4);
        float d = 0.f;
#pragma unroll
        for (int q = 0; q < 4; ++q)
            d += ev[q].x * qv[q].x + ev[q].y * qv[q].y + ev[q].z * qv[q].z + ev[q].w * qv[q].w;
#pragma unroll
        for (int off = 32; off >= 1; off >>= 1) d += __shfl_xor(d, off);
        if (lane == 0) energy[(size_t)b * Lw + l] = d;

        if (d > m) {                       // wave-uniform branch, rare after warmup
            float sc = expf(m - d);
            s *= sc;
#pragma unroll
            for (int q = 0; q < 4; ++q) {
                ctx[q].x *= sc; ctx[q].y *= sc; ctx[q].z *= sc; ctx[q].w *= sc;
            }
            m = d;
        }
        float w = expf(d - m);
        s += w;
#pragma unroll
        for (int q = 0; q < 4; ++q) {
            ctx[q].x += w * ev[q].x; ctx[q].y += w * ev[q].y;
            ctx[q].z += w * ev[q].z; ctx[q].w += w * ev[q].w;
        }
    }

    // combine the 4 waves of this block
    __shared__ float lctx[4][Hd];
    __shared__ float lms[4][2];
#pragma unroll
    for (int q = 0; q < 4; ++q)
        *(float4*)(&lctx[wave][q * 256 + lane * 4]) = ctx[q];
    if (lane == 0) { lms[wave][0] = m; lms[wave][1] = s; }
    __syncthreads();

    float mb = fmaxf(fmaxf(lms[0][0], lms[1][0]), fmaxf(lms[2][0], lms[3][0]));
    float sc0 = expf(lms[0][0] - mb), sc1 = expf(lms[1][0] - mb);
    float sc2 = expf(lms[2][0] - mb), sc3 = expf(lms[3][0] - mb);
    float sb = lms[0][1] * sc0 + lms[1][1] * sc1 + lms[2][1] * sc2 + lms[3][1] * sc3;

    int t = threadIdx.x;
    float* pb = part + (size_t)(chunk * B + b) * PSTRIDE;
    float4 a0 = *(float4*)(&lctx[0][t * 4]);
    float4 a1 = *(float4*)(&lctx[1][t * 4]);
    float4 a2 = *(float4*)(&lctx[2][t * 4]);
    float4 a3 = *(float4*)(&lctx[3][t * 4]);
    float4 v;
    v.x = a0.x * sc0 + a1.x * sc1 + a2.x * sc2 + a3.x * sc3;
    v.y = a0.y * sc0 + a1.y * sc1 + a2.y * sc2 + a3.y * sc3;
    v.z = a0.z * sc0 + a1.z * sc1 + a2.z * sc2 + a3.z * sc3;
    v.w = a0.w * sc0 + a1.w * sc1 + a2.w * sc2 + a3.w * sc3;
    *(float4*)(pb + t * 4) = v;
    if (t == 0) { pb[1024] = mb; pb[1025] = sb; }
}

// ---------------- merge chunk partials -> context (packed into cat second half) + (m,s)
__global__ void k_attn_combine(const float* __restrict__ part, float* __restrict__ cat,
                               float* __restrict__ ms)
{
    int b = blockIdx.x, t = threadIdx.x;
    float m = -INFINITY;
#pragma unroll
    for (int c = 0; c < NCHUNK; ++c)
        m = fmaxf(m, part[(size_t)(c * B + b) * PSTRIDE + 1024]);
    float s = 0.f, scl[NCHUNK];
#pragma unroll
    for (int c = 0; c < NCHUNK; ++c) {
        const float* pb = part + (size_t)(c * B + b) * PSTRIDE;
        scl[c] = expf(pb[1024] - m);
        s += pb[1025] * scl[c];
    }
    float4 v = make_float4(0.f, 0.f, 0.f, 0.f);
#pragma unroll
    for (int c = 0; c < NCHUNK; ++c) {
        float4 p = *(const float4*)(part + (size_t)(c * B + b) * PSTRIDE + t * 4);
        v.x += p.x * scl[c]; v.y += p.y * scl[c]; v.z += p.z * scl[c]; v.w += p.w * scl[c];
    }
    float inv = 1.f / s;
    v.x *= inv; v.y *= inv; v.z *= inv; v.w *= inv;
    ((float4*)cat)[(256 + t) * B + b] = v;      // k = 1024 + t*4 (context part)
    if (t == 0) { ms[b * 2] = m; ms[b * 2 + 1] = s; }
}

// ---------------- attn output normalize
__global__ void k_attn_norm(const float* __restrict__ energy, const float* __restrict__ ms,
                            float* __restrict__ attn)
{
    int idx = blockIdx.x * blockDim.x + threadIdx.x;   // [0, 131072)
    int b = idx >> 11;
    float m = ms[b * 2], s = ms[b * 2 + 1];
    attn[idx] = expf(energy[idx] - m) / s;
}

extern "C" void kernel_launch(void* const* d_in, const int* in_sizes, int n_in,
                              void* d_out, int out_size, void* d_ws, size_t ws_size,
                              hipStream_t stream)
{
    const int*   seq    = (const int*)d_in[0];
    const float* enc    = (const float*)d_in[1];
    const float* h0     = (const float*)d_in[2];
    const float* c0     = (const float*)d_in[3];
    const float* emb    = (const float*)d_in[4];
    const float* W_ih   = (const float*)d_in[5];
    const float* W_hh   = (const float*)d_in[6];
    const float* b_ih   = (const float*)d_in[7];
    const float* b_hh   = (const float*)d_in[8];
    const float* W_cat  = (const float*)d_in[9];
    const float* b_cat  = (const float*)d_in[10];
    const float* W_out  = (const float*)d_in[11];
    const float* b_out  = (const float*)d_in[12];
    float* out = (float*)d_out;
    float* ws  = (float*)d_ws;

    float* xh     = ws + WS_XH4;
    float* gatesT = ws + WS_GATES;
    float* cat    = ws + WS_CAT4;
    float* energy = ws + WS_ENERGY;
    float* part   = ws + WS_PART;
    float* ms     = ws + WS_MS;
    float* conc   = ws + WS_CONCAT;

    k_embed<<<B, 256, 0, stream>>>(seq, emb, h0, xh);
    // gates = [x;h] @ [W_ih | W_hh]^T + b_ih + b_hh : N=4096, K=1024+1024
    k_gemm<1024, 1024, 4, 0><<<256, 256, 0, stream>>>(
        (const float4*)xh, W_ih, W_hh, b_ih, b_hh, 4 * Hd, gatesT, 0);
    k_pointwise<<<256, 256, 0, stream>>>(gatesT, c0, out + OUT_H1, out + OUT_C1, cat);
    k_attn_part<<<dim3(NCHUNK, B), 256, 0, stream>>>(enc, out + OUT_H1, energy, part);
    k_attn_combine<<<B, 256, 0, stream>>>(part, cat, ms);
    k_attn_norm<<<512, 256, 0, stream>>>(energy, ms, out + OUT_ATTN);
    // concat_out = tanh([h1;ctx] @ W_concat^T + b) : N=1024, K=2048
    k_gemm<2048, 0, 2, 1><<<128, 256, 0, stream>>>(
        (const float4*)cat, W_cat, nullptr, b_cat, nullptr, Hd, conc, 0);
    // output = concat_out @ W_out^T + b_out : N=50257, K=1024
    k_gemm<1024, 0, 8, 2><<<1571, 256, 0, stream>>>(
        (const float4*)conc, W_out, nullptr, b_out, nullptr, Vd, out, Vd);
}

// Round 2
// 581.571 us; speedup vs baseline: 1.8542x; 1.8542x over previous
//
#include <hip/hip_runtime.h>
#include <math.h>

#define B 64
#define Lw 2048
#define Hd 1024
#define Vd 50257

// ws offsets (in floats)
#define WS_XH4    0          // packed [x;h] activations: 2048*64 = 131072
#define WS_GATES  131072     // gatesT [4096][64]        = 262144
#define WS_CAT4   393216     // packed [h1;context]      = 131072
#define WS_ENERGY 524288     // energies [64][2048]      = 131072
#define WS_PART   655360     // 16*64 partials * 1032    = 1056768
#define WS_MS     1712128    // per-b (m, s)             = 128
#define WS_CONCAT 1712256    // packed concat_out        = 65536

// d_out offsets (floats): output[B][V], h1[1][B][H], c1[1][B][H], attn[B][1][L]
#define OUT_H1   3216448
#define OUT_C1   3281984
#define OUT_ATTN 3347520

#define NCHUNK 16
#define LCHUNK 128
#define PSTRIDE 1032

__device__ __forceinline__ float sigm(float x) { return 1.f / (1.f + expf(-x)); }

// ---------------- embed + pack [x ; h_prev] transposed: xh4[(k/4)*256 + b*4 + k%4]
__global__ void k_embed(const int* __restrict__ seq, const float* __restrict__ emb,
                        const float* __restrict__ h0, float* __restrict__ xh)
{
    int b = blockIdx.x;
    int t = threadIdx.x;               // handles h = t*4 .. t*4+3
    int tok = seq[b];
    float4 xv = *(const float4*)(emb + (size_t)tok * Hd + t * 4);
    float4 hv = *(const float4*)(h0 + (size_t)b * Hd + t * 4);
    ((float4*)xh)[t * B + b] = xv;            // k = t*4 (x part)
    ((float4*)xh)[(256 + t) * B + b] = hv;    // k = 1024 + t*4 (h part)
}

// ---------------- skinny GEMM with LDS weight broadcast
// out[b, row] = act[b, :] . W[row, :] (+bias).  lane = b.
// Each wave owns ROWS rows. Per K-chunk (KC4*4 floats):
//   stage: coalesced per-lane float4 loads of W chunk -> per-wave LDS region
//   compute: wave-uniform ds_read_b128 broadcast of W + coalesced act stream
// MODE 0: gatesT store [row][B], bias1+bias2
// MODE 1: tanh, packed4 store (feeds next GEMM), bias1
// MODE 2: plain [b][row] store (d_out), bias1
template<int K1, int K2, int ROWS, int KC4, int MODE>
__global__ void k_gemm(const float4* __restrict__ act,
                       const float* __restrict__ W1, const float* __restrict__ W2,
                       const float* __restrict__ b1, const float* __restrict__ b2,
                       int N, float* __restrict__ out, int ldout)
{
    constexpr int KC   = KC4 * 4;              // floats per chunk
    constexpr int NCH  = (K1 + K2) / KC;       // chunks
    constexpr int NL   = ROWS * KC4 / 64;      // float4 stage loads per lane
    constexpr int RPL  = 64 / KC4;             // rows covered per stage load iter
    static_assert(ROWS * KC4 % 64 == 0, "stage divisibility");
    static_assert(K1 % KC == 0 && K2 % KC == 0, "chunk divisibility");

    __shared__ float4 lw[4 * ROWS * KC4];

    int wave = threadIdx.x >> 6;
    int lane = threadIdx.x & 63;
    int r0 = (blockIdx.x * 4 + wave) * ROWS;
    if (r0 >= N) return;
    int rm = N - r0;                            // valid rows (>=1)

    float4* lwp = lw + wave * (ROWS * KC4);

    float acc[ROWS];
#pragma unroll
    for (int r = 0; r < ROWS; ++r) acc[r] = 0.f;

#pragma unroll
    for (int c = 0; c < NCH; ++c) {
        const float* Wsrc;
        int koff, kstr;
        if constexpr (K2 > 0) {
            if (c * KC < K1) { Wsrc = W1; koff = c * KC;      kstr = K1; }
            else             { Wsrc = W2; koff = c * KC - K1; kstr = K2; }
        } else {
            Wsrc = W1; koff = c * KC; kstr = K1;
        }

        // ---- stage W chunk (coalesced)
        float4 wst[NL];
#pragma unroll
        for (int j = 0; j < NL; ++j) {
            int idx = j * 64 + lane;
            int r, c4;
            if constexpr (KC4 == 64) { r = j;                        c4 = lane; }
            else                     { r = j * RPL + (lane / KC4);   c4 = lane % KC4; }
            int row = r0 + r; if (row > N - 1) row = N - 1;          // clamp (dup ok)
            wst[j] = *(const float4*)(Wsrc + (size_t)row * kstr + koff + c4 * 4);
            (void)idx;
        }
        asm volatile("s_waitcnt lgkmcnt(0)" ::: "memory");   // prior chunk's reads done
#pragma unroll
        for (int j = 0; j < NL; ++j)
            lwp[j * 64 + lane] = wst[j];
        asm volatile("s_waitcnt lgkmcnt(0)" ::: "memory");   // writes visible to wave

        // ---- compute
#pragma unroll 8
        for (int k4 = 0; k4 < KC4; ++k4) {
            float4 a = act[(c * KC4 + k4) * B + lane];
#pragma unroll
            for (int r = 0; r < ROWS; ++r) {
                float4 w = lwp[r * KC4 + k4];                // broadcast
                acc[r] += a.x * w.x + a.y * w.y + a.z * w.z + a.w * w.w;
            }
        }
    }

#pragma unroll
    for (int r = 0; r < ROWS; ++r) {
        if (r < rm) {
            int row = r0 + r;
            if constexpr (MODE == 0) {
                out[(size_t)row * B + lane] = acc[r] + b1[row] + b2[row];
            } else if constexpr (MODE == 1) {
                out[(row >> 2) * 256 + lane * 4 + (row & 3)] = tanhf(acc[r] + b1[row]);
            } else {
                out[(size_t)lane * ldout + row] = acc[r] + b1[row];
            }
        }
    }
}

// ---------------- LSTM pointwise (PyTorch gate order i,f,g,o)
__global__ void k_pointwise(const float* __restrict__ gatesT, const float* __restrict__ c0,
                            float* __restrict__ h1o, float* __restrict__ c1o,
                            float* __restrict__ cat)
{
    int wave = threadIdx.x >> 6, lane = threadIdx.x & 63;
    int hh = blockIdx.x * 4 + wave;
    float gi = gatesT[(size_t)(0 * Hd + hh) * B + lane];
    float gf = gatesT[(size_t)(1 * Hd + hh) * B + lane];
    float gg = gatesT[(size_t)(2 * Hd + hh) * B + lane];
    float go = gatesT[(size_t)(3 * Hd + hh) * B + lane];
    float c  = c0[(size_t)lane * Hd + hh];
    float c1 = sigm(gf) * c + sigm(gi) * tanhf(gg);
    float h1 = sigm(go) * tanhf(c1);
    h1o[(size_t)lane * Hd + hh] = h1;
    c1o[(size_t)lane * Hd + hh] = c1;
    cat[(hh >> 2) * 256 + lane * 4 + (hh & 3)] = h1;   // packed, k = hh
}

// ---------------- fused energies + online-softmax context partials (one enc pass)
__global__ void k_attn_part(const float* __restrict__ enc, const float* __restrict__ h1,
                            float* __restrict__ energy, float* __restrict__ part)
{
    int chunk = blockIdx.x, b = blockIdx.y;
    int wave = threadIdx.x >> 6, lane = threadIdx.x & 63;

    float4 qv[4], ctx[4];
#pragma unroll
    for (int q = 0; q < 4; ++q) {
        qv[q] = *(const float4*)(h1 + (size_t)b * Hd + q * 256 + lane * 4);
        ctx[q] = make_float4(0.f, 0.f, 0.f, 0.f);
    }
    float m = -INFINITY, s = 0.f;

    for (int i = 0; i < LCHUNK / 4; ++i) {
        int l = chunk * LCHUNK + i * 4 + wave;
        const float* ep = enc + ((size_t)l * B + b) * Hd;
        float4 ev[4];
#pragma unroll
        for (int q = 0; q < 4; ++q) ev[q] = *(const float4*)(ep + q * 256 + lane * 4);
        float d = 0.f;
#pragma unroll
        for (int q = 0; q < 4; ++q)
            d += ev[q].x * qv[q].x + ev[q].y * qv[q].y + ev[q].z * qv[q].z + ev[q].w * qv[q].w;
#pragma unroll
        for (int off = 32; off >= 1; off >>= 1) d += __shfl_xor(d, off);
        if (lane == 0) energy[(size_t)b * Lw + l] = d;

        if (d > m) {                       // wave-uniform branch, rare after warmup
            float sc = expf(m - d);
            s *= sc;
#pragma unroll
            for (int q = 0; q < 4; ++q) {
                ctx[q].x *= sc; ctx[q].y *= sc; ctx[q].z *= sc; ctx[q].w *= sc;
            }
            m = d;
        }
        float w = expf(d - m);
        s += w;
#pragma unroll
        for (int q = 0; q < 4; ++q) {
            ctx[q].x += w * ev[q].x; ctx[q].y += w * ev[q].y;
            ctx[q].z += w * ev[q].z; ctx[q].w += w * ev[q].w;
        }
    }

    // combine the 4 waves of this block
    __shared__ float lctx[4][Hd];
    __shared__ float lms[4][2];
#pragma unroll
    for (int q = 0; q < 4; ++q)
        *(float4*)(&lctx[wave][q * 256 + lane * 4]) = ctx[q];
    if (lane == 0) { lms[wave][0] = m; lms[wave][1] = s; }
    __syncthreads();

    float mb = fmaxf(fmaxf(lms[0][0], lms[1][0]), fmaxf(lms[2][0], lms[3][0]));
    float sc0 = expf(lms[0][0] - mb), sc1 = expf(lms[1][0] - mb);
    float sc2 = expf(lms[2][0] - mb), sc3 = expf(lms[3][0] - mb);
    float sb = lms[0][1] * sc0 + lms[1][1] * sc1 + lms[2][1] * sc2 + lms[3][1] * sc3;

    int t = threadIdx.x;
    float* pb = part + (size_t)(chunk * B + b) * PSTRIDE;
    float4 a0 = *(float4*)(&lctx[0][t * 4]);
    float4 a1 = *(float4*)(&lctx[1][t * 4]);
    float4 a2 = *(float4*)(&lctx[2][t * 4]);
    float4 a3 = *(float4*)(&lctx[3][t * 4]);
    float4 v;
    v.x = a0.x * sc0 + a1.x * sc1 + a2.x * sc2 + a3.x * sc3;
    v.y = a0.y * sc0 + a1.y * sc1 + a2.y * sc2 + a3.y * sc3;
    v.z = a0.z * sc0 + a1.z * sc1 + a2.z * sc2 + a3.z * sc3;
    v.w = a0.w * sc0 + a1.w * sc1 + a2.w * sc2 + a3.w * sc3;
    *(float4*)(pb + t * 4) = v;
    if (t == 0) { pb[1024] = mb; pb[1025] = sb; }
}

// ---------------- merge chunk partials -> context (packed into cat second half) + (m,s)
__global__ void k_attn_combine(const float* __restrict__ part, float* __restrict__ cat,
                               float* __restrict__ ms)
{
    int b = blockIdx.x, t = threadIdx.x;
    float m = -INFINITY;
#pragma unroll
    for (int c = 0; c < NCHUNK; ++c)
        m = fmaxf(m, part[(size_t)(c * B + b) * PSTRIDE + 1024]);
    float s = 0.f, scl[NCHUNK];
#pragma unroll
    for (int c = 0; c < NCHUNK; ++c) {
        const float* pb = part + (size_t)(c * B + b) * PSTRIDE;
        scl[c] = expf(pb[1024] - m);
        s += pb[1025] * scl[c];
    }
    float4 v = make_float4(0.f, 0.f, 0.f, 0.f);
#pragma unroll
    for (int c = 0; c < NCHUNK; ++c) {
        float4 p = *(const float4*)(part + (size_t)(c * B + b) * PSTRIDE + t * 4);
        v.x += p.x * scl[c]; v.y += p.y * scl[c]; v.z += p.z * scl[c]; v.w += p.w * scl[c];
    }
    float inv = 1.f / s;
    v.x *= inv; v.y *= inv; v.z *= inv; v.w *= inv;
    ((float4*)cat)[(256 + t) * B + b] = v;      // k = 1024 + t*4 (context part)
    if (t == 0) { ms[b * 2] = m; ms[b * 2 + 1] = s; }
}

// ---------------- attn output normalize
__global__ void k_attn_norm(const float* __restrict__ energy, const float* __restrict__ ms,
                            float* __restrict__ attn)
{
    int idx = blockIdx.x * blockDim.x + threadIdx.x;   // [0, 131072)
    int b = idx >> 11;
    float m = ms[b * 2], s = ms[b * 2 + 1];
    attn[idx] = expf(energy[idx] - m) / s;
}

extern "C" void kernel_launch(void* const* d_in, const int* in_sizes, int n_in,
                              void* d_out, int out_size, void* d_ws, size_t ws_size,
                              hipStream_t stream)
{
    const int*   seq    = (const int*)d_in[0];
    const float* enc    = (const float*)d_in[1];
    const float* h0     = (const float*)d_in[2];
    const float* c0     = (const float*)d_in[3];
    const float* emb    = (const float*)d_in[4];
    const float* W_ih   = (const float*)d_in[5];
    const float* W_hh   = (const float*)d_in[6];
    const float* b_ih   = (const float*)d_in[7];
    const float* b_hh   = (const float*)d_in[8];
    const float* W_cat  = (const float*)d_in[9];
    const float* b_cat  = (const float*)d_in[10];
    const float* W_out  = (const float*)d_in[11];
    const float* b_out  = (const float*)d_in[12];
    float* out = (float*)d_out;
    float* ws  = (float*)d_ws;

    float* xh     = ws + WS_XH4;
    float* gatesT = ws + WS_GATES;
    float* cat    = ws + WS_CAT4;
    float* energy = ws + WS_ENERGY;
    float* part   = ws + WS_PART;
    float* ms     = ws + WS_MS;
    float* conc   = ws + WS_CONCAT;

    k_embed<<<B, 256, 0, stream>>>(seq, emb, h0, xh);
    // gates = [x;h] @ [W_ih | W_hh]^T + b_ih + b_hh : N=4096, K=1024+1024
    // ROWS=4, KC4=64 -> 16 rows/block, 256 blocks
    k_gemm<1024, 1024, 4, 64, 0><<<256, 256, 0, stream>>>(
        (const float4*)xh, W_ih, W_hh, b_ih, b_hh, 4 * Hd, gatesT, 0);
    k_pointwise<<<256, 256, 0, stream>>>(gatesT, c0, out + OUT_H1, out + OUT_C1, cat);
    k_attn_part<<<dim3(NCHUNK, B), 256, 0, stream>>>(enc, out + OUT_H1, energy, part);
    k_attn_combine<<<B, 256, 0, stream>>>(part, cat, ms);
    k_attn_norm<<<512, 256, 0, stream>>>(energy, ms, out + OUT_ATTN);
    // concat_out = tanh([h1;ctx] @ W_concat^T + b) : N=1024, K=2048
    // ROWS=2, KC4=64 -> 8 rows/block, 128 blocks
    k_gemm<2048, 0, 2, 64, 1><<<128, 256, 0, stream>>>(
        (const float4*)cat, W_cat, nullptr, b_cat, nullptr, Hd, conc, 0);
    // output = concat_out @ W_out^T + b_out : N=50257, K=1024
    // ROWS=16, KC4=32 -> 64 rows/block, ceil(50257/64)=786 blocks
    k_gemm<1024, 0, 16, 32, 2><<<786, 256, 0, stream>>>(
        (const float4*)conc, W_out, nullptr, b_out, nullptr, Vd, out, Vd);
}